// Round 1
// baseline (2614.225 us; speedup 1.0000x reference)
//
#include <hip/hip_runtime.h>
#include <math.h>

// B=4, H=W=64, C=256, Ck=32, N=H*W=4096, M=B*N=16384
// ws layout (floats): f[M*32] | g[M*32] | hm[M*256] | o[M*256]  (~37.7 MB)

// ---------------------------------------------------------------------------
// Generic fp32 GEMM: out[M,Nc] = A[M,K] @ W[K,Nc] + bias (+ res)
// 128x128 tile, 16x16 threads, 8x8 microtile, K-chunk 16.
// At stored transposed [k][row] so fragment reads are aligned float4.
// ---------------------------------------------------------------------------
__global__ __launch_bounds__(256) void gemm128(
    const float* __restrict__ A, const float* __restrict__ W,
    const float* __restrict__ bias, const float* __restrict__ res,
    float* __restrict__ out, int M, int K, int Nc)
{
    __shared__ float At[16][132];   // [k][row], pad 132
    __shared__ float Wt[16][132];   // [k][n],   pad 132

    const int t  = threadIdx.x;
    const int tx = t & 15, ty = t >> 4;
    const int bm = blockIdx.x * 128;
    const int bn = blockIdx.y * 128;

    float acc[8][8];
#pragma unroll
    for (int i = 0; i < 8; ++i)
#pragma unroll
        for (int j = 0; j < 8; ++j) acc[i][j] = 0.f;

    for (int k0 = 0; k0 < K; k0 += 16) {
        // stage A tile: 128 rows x 16 k  (512 float4)
#pragma unroll
        for (int it = 0; it < 2; ++it) {
            int idx4 = t + 256 * it;
            int row  = idx4 >> 2;
            int c4   = (idx4 & 3) << 2;
            float4 v = *reinterpret_cast<const float4*>(
                A + (size_t)(bm + row) * K + k0 + c4);
            At[c4 + 0][row] = v.x;
            At[c4 + 1][row] = v.y;
            At[c4 + 2][row] = v.z;
            At[c4 + 3][row] = v.w;
        }
        // stage W tile: 16 k x 128 n (512 float4), zero-fill past Nc
#pragma unroll
        for (int it = 0; it < 2; ++it) {
            int idx4 = t + 256 * it;
            int k    = idx4 >> 5;
            int n4   = (idx4 & 31) << 2;
            float4 v;
            if (bn + n4 + 3 < Nc)
                v = *reinterpret_cast<const float4*>(
                    W + (size_t)(k0 + k) * Nc + bn + n4);
            else
                v = make_float4(0.f, 0.f, 0.f, 0.f);
            *reinterpret_cast<float4*>(&Wt[k][n4]) = v;
        }
        __syncthreads();

#pragma unroll
        for (int k = 0; k < 16; ++k) {
            float4 a0 = *reinterpret_cast<const float4*>(&At[k][ty * 8]);
            float4 a1 = *reinterpret_cast<const float4*>(&At[k][ty * 8 + 4]);
            float4 w0 = *reinterpret_cast<const float4*>(&Wt[k][tx * 8]);
            float4 w1 = *reinterpret_cast<const float4*>(&Wt[k][tx * 8 + 4]);
            float a[8] = {a0.x, a0.y, a0.z, a0.w, a1.x, a1.y, a1.z, a1.w};
            float w[8] = {w0.x, w0.y, w0.z, w0.w, w1.x, w1.y, w1.z, w1.w};
#pragma unroll
            for (int i = 0; i < 8; ++i)
#pragma unroll
                for (int j = 0; j < 8; ++j)
                    acc[i][j] = fmaf(a[i], w[j], acc[i][j]);
        }
        __syncthreads();
    }

    // epilogue: bias (+ residual), float4 stores, guard Nc
#pragma unroll
    for (int i = 0; i < 8; ++i) {
        int row = bm + ty * 8 + i;
#pragma unroll
        for (int j4 = 0; j4 < 2; ++j4) {
            int col = bn + tx * 8 + j4 * 4;
            if (col + 3 < Nc) {
                float4 v;
                v.x = acc[i][j4 * 4 + 0] + bias[col + 0];
                v.y = acc[i][j4 * 4 + 1] + bias[col + 1];
                v.z = acc[i][j4 * 4 + 2] + bias[col + 2];
                v.w = acc[i][j4 * 4 + 3] + bias[col + 3];
                if (res) {
                    float4 r = *reinterpret_cast<const float4*>(
                        res + (size_t)row * Nc + col);
                    v.x += r.x; v.y += r.y; v.z += r.z; v.w += r.w;
                }
                *reinterpret_cast<float4*>(out + (size_t)row * Nc + col) = v;
            }
        }
    }
}

// ---------------------------------------------------------------------------
// Flash-style fused attention (fp32):
//   per block: batch b, 64 query rows. Loop over 128 key-tiles of 32 keys.
//   s = g @ f^T (Ck=32), online softmax, o += p @ hm (C=256).
// thread t: r = t&63 (query row), cg = t>>6 (64-col group of o).
// ---------------------------------------------------------------------------
__global__ __launch_bounds__(256) void attn_flash(
    const float* __restrict__ f, const float* __restrict__ g,
    const float* __restrict__ hm, float* __restrict__ o)
{
    const int N = 4096;
    __shared__ float f_t[32 * 32];        // [m][k] flat, broadcast reads
    __shared__ float s_t[64][33];         // padded: conflict-free row reads
    __shared__ float hm_t[32 * 260];      // [m][c] pad 260, broadcast reads

    const int t  = threadIdx.x;
    const int r  = t & 63;
    const int cg = t >> 6;
    const int b  = blockIdx.x >> 6;       // 64 query tiles per batch
    const int qt = blockIdx.x & 63;

    // g row for this thread's query into registers (32 floats)
    float greg[32];
    {
        const float4* gp = reinterpret_cast<const float4*>(
            g + ((size_t)b * N + qt * 64 + r) * 32);
#pragma unroll
        for (int i = 0; i < 8; ++i) {
            float4 v = gp[i];
            greg[4 * i + 0] = v.x; greg[4 * i + 1] = v.y;
            greg[4 * i + 2] = v.z; greg[4 * i + 3] = v.w;
        }
    }

    float mrun = -3.0e38f, lrun = 0.f;
    float oacc[64];
#pragma unroll
    for (int j = 0; j < 64; ++j) oacc[j] = 0.f;

    for (int kt = 0; kt < N / 32; ++kt) {
        // stage f tile: 32x32 = 256 float4 (1/thread), coalesced
        {
            const float4* fp = reinterpret_cast<const float4*>(
                f + ((size_t)b * N + kt * 32) * 32);
            reinterpret_cast<float4*>(f_t)[t] = fp[t];
        }
        // stage hm tile: 32x256 = 2048 float4 (8/thread), coalesced
        {
            const float4* hp = reinterpret_cast<const float4*>(
                hm + ((size_t)b * N + kt * 32) * 256);
#pragma unroll
            for (int i = 0; i < 8; ++i) {
                int idx4 = t + 256 * i;
                int m    = idx4 >> 6;
                int c4   = (idx4 & 63) << 2;
                *reinterpret_cast<float4*>(hm_t + m * 260 + c4) = hp[idx4];
            }
        }
        __syncthreads();

        // s[r][m] for m = cg*8 .. cg*8+7
#pragma unroll
        for (int i = 0; i < 8; ++i) {
            int m = cg * 8 + i;
            const float* fr = f_t + m * 32;
            float acc = 0.f;
#pragma unroll
            for (int k4 = 0; k4 < 8; ++k4) {
                float4 fv = *reinterpret_cast<const float4*>(fr + 4 * k4);
                acc = fmaf(greg[4 * k4 + 0], fv.x, acc);
                acc = fmaf(greg[4 * k4 + 1], fv.y, acc);
                acc = fmaf(greg[4 * k4 + 2], fv.z, acc);
                acc = fmaf(greg[4 * k4 + 3], fv.w, acc);
            }
            s_t[r][m] = acc;
        }
        __syncthreads();

        // online softmax update (each of 4 threads sharing row r computes
        // identical stats from identical LDS reads -> consistent)
        float mloc = mrun;
#pragma unroll
        for (int m = 0; m < 32; ++m) mloc = fmaxf(mloc, s_t[r][m]);
        float mnew  = mloc;
        float alpha = __expf(mrun - mnew);   // first iter: exp(-inf) = 0
        lrun *= alpha;
#pragma unroll
        for (int j = 0; j < 64; ++j) oacc[j] *= alpha;

#pragma unroll 2
        for (int m = 0; m < 32; ++m) {
            float pm = __expf(s_t[r][m] - mnew);
            lrun += pm;
            const float* hrow = hm_t + m * 260 + cg * 64;
#pragma unroll
            for (int j4 = 0; j4 < 16; ++j4) {
                float4 h = *reinterpret_cast<const float4*>(hrow + 4 * j4);
                oacc[4 * j4 + 0] = fmaf(pm, h.x, oacc[4 * j4 + 0]);
                oacc[4 * j4 + 1] = fmaf(pm, h.y, oacc[4 * j4 + 1]);
                oacc[4 * j4 + 2] = fmaf(pm, h.z, oacc[4 * j4 + 2]);
                oacc[4 * j4 + 3] = fmaf(pm, h.w, oacc[4 * j4 + 3]);
            }
        }
        mrun = mnew;
        __syncthreads();
    }

    float inv = 1.f / lrun;
    float* orow = o + ((size_t)b * N + qt * 64 + r) * 256 + cg * 64;
#pragma unroll
    for (int j4 = 0; j4 < 16; ++j4) {
        float4 v;
        v.x = oacc[4 * j4 + 0] * inv;
        v.y = oacc[4 * j4 + 1] * inv;
        v.z = oacc[4 * j4 + 2] * inv;
        v.w = oacc[4 * j4 + 3] * inv;
        reinterpret_cast<float4*>(orow)[j4] = v;
    }
}

// ---------------------------------------------------------------------------
extern "C" void kernel_launch(void* const* d_in, const int* in_sizes, int n_in,
                              void* d_out, int out_size, void* d_ws, size_t ws_size,
                              hipStream_t stream)
{
    const float* x  = (const float*)d_in[0];
    const float* Wf = (const float*)d_in[1];
    const float* bf = (const float*)d_in[2];
    const float* Wg = (const float*)d_in[3];
    const float* bg = (const float*)d_in[4];
    const float* Wh = (const float*)d_in[5];
    const float* bh = (const float*)d_in[6];
    const float* Wv = (const float*)d_in[7];
    const float* bv = (const float*)d_in[8];
    float* out = (float*)d_out;

    const int B = 4, N = 4096, C = 256, Ck = 32;
    const int M = B * N;  // 16384

    float* fbuf = (float*)d_ws;
    float* gbuf = fbuf + (size_t)M * Ck;
    float* hbuf = gbuf + (size_t)M * Ck;
    float* obuf = hbuf + (size_t)M * C;

    dim3 blk(256);

    // projections: f = x@Wf+bf, g = x@Wg+bg, hm = x@Wh+bh
    gemm128<<<dim3(M / 128, 1), blk, 0, stream>>>(x, Wf, bf, nullptr, fbuf, M, C, Ck);
    gemm128<<<dim3(M / 128, 1), blk, 0, stream>>>(x, Wg, bg, nullptr, gbuf, M, C, Ck);
    gemm128<<<dim3(M / 128, 2), blk, 0, stream>>>(x, Wh, bh, nullptr, hbuf, M, C, C);

    // fused attention: o = softmax(g f^T) hm
    attn_flash<<<dim3(B * (N / 64)), blk, 0, stream>>>(fbuf, gbuf, hbuf, obuf);

    // out = x + o@Wv + bv
    gemm128<<<dim3(M / 128, 2), blk, 0, stream>>>(obuf, Wv, bv, x, out, M, C, C);
}

// Round 2
// 366.034 us; speedup vs baseline: 7.1420x; 7.1420x over previous
//
#include <hip/hip_runtime.h>
#include <math.h>

// B=4, H=W=64, C=256, Ck=32, N=4096, M=B*N=16384
// ws (bytes): fg bf16 [4][4096][64]   = 2 MB   (f = cols 0..31, g = cols 32..63)
//             hm_t bf16 [4][256][4096]= 8 MB   (channel-major for V B-frags)
//             obuf f32 [16384][256]   = 16 MB

typedef unsigned short u16;
typedef __attribute__((ext_vector_type(8))) short  bf16x8;
typedef __attribute__((ext_vector_type(4))) float  f32x4;

__device__ inline u16 f2bf(float x) {
    unsigned u = __float_as_uint(x);
    unsigned r = (u + 0x7fffu + ((u >> 16) & 1u)) >> 16;
    return (u16)r;
}

#define ASYNC_CP16(gp, lp)                                                     \
    __builtin_amdgcn_global_load_lds(                                          \
        (const __attribute__((address_space(1))) void*)(gp),                   \
        (__attribute__((address_space(3))) void*)(lp), 16, 0, 0)

// ---------------------------------------------------------------------------
// fp32 GEMM (final conv): out[M,Nc] = A[M,K] @ W[K,Nc] + bias (+ res)
// ---------------------------------------------------------------------------
__global__ __launch_bounds__(256) void gemm128(
    const float* __restrict__ A, const float* __restrict__ W,
    const float* __restrict__ bias, const float* __restrict__ res,
    float* __restrict__ out, int M, int K, int Nc)
{
    __shared__ float At[16][132];
    __shared__ float Wt[16][132];

    const int t  = threadIdx.x;
    const int tx = t & 15, ty = t >> 4;
    const int bm = blockIdx.x * 128;
    const int bn = blockIdx.y * 128;

    float acc[8][8];
#pragma unroll
    for (int i = 0; i < 8; ++i)
#pragma unroll
        for (int j = 0; j < 8; ++j) acc[i][j] = 0.f;

    for (int k0 = 0; k0 < K; k0 += 16) {
#pragma unroll
        for (int it = 0; it < 2; ++it) {
            int idx4 = t + 256 * it;
            int row  = idx4 >> 2;
            int c4   = (idx4 & 3) << 2;
            float4 v = *reinterpret_cast<const float4*>(
                A + (size_t)(bm + row) * K + k0 + c4);
            At[c4 + 0][row] = v.x; At[c4 + 1][row] = v.y;
            At[c4 + 2][row] = v.z; At[c4 + 3][row] = v.w;
        }
#pragma unroll
        for (int it = 0; it < 2; ++it) {
            int idx4 = t + 256 * it;
            int k    = idx4 >> 5;
            int n4   = (idx4 & 31) << 2;
            float4 v = *reinterpret_cast<const float4*>(
                W + (size_t)(k0 + k) * Nc + bn + n4);
            *reinterpret_cast<float4*>(&Wt[k][n4]) = v;
        }
        __syncthreads();

#pragma unroll
        for (int k = 0; k < 16; ++k) {
            float4 a0 = *reinterpret_cast<const float4*>(&At[k][ty * 8]);
            float4 a1 = *reinterpret_cast<const float4*>(&At[k][ty * 8 + 4]);
            float4 w0 = *reinterpret_cast<const float4*>(&Wt[k][tx * 8]);
            float4 w1 = *reinterpret_cast<const float4*>(&Wt[k][tx * 8 + 4]);
            float a[8] = {a0.x, a0.y, a0.z, a0.w, a1.x, a1.y, a1.z, a1.w};
            float w[8] = {w0.x, w0.y, w0.z, w0.w, w1.x, w1.y, w1.z, w1.w};
#pragma unroll
            for (int i = 0; i < 8; ++i)
#pragma unroll
                for (int j = 0; j < 8; ++j)
                    acc[i][j] = fmaf(a[i], w[j], acc[i][j]);
        }
        __syncthreads();
    }

#pragma unroll
    for (int i = 0; i < 8; ++i) {
        int row = bm + ty * 8 + i;
#pragma unroll
        for (int j4 = 0; j4 < 2; ++j4) {
            int col = bn + tx * 8 + j4 * 4;
            float4 v;
            v.x = acc[i][j4 * 4 + 0] + bias[col + 0];
            v.y = acc[i][j4 * 4 + 1] + bias[col + 1];
            v.z = acc[i][j4 * 4 + 2] + bias[col + 2];
            v.w = acc[i][j4 * 4 + 3] + bias[col + 3];
            if (res) {
                float4 r = *reinterpret_cast<const float4*>(
                    res + (size_t)row * Nc + col);
                v.x += r.x; v.y += r.y; v.z += r.z; v.w += r.w;
            }
            *reinterpret_cast<float4*>(out + (size_t)row * Nc + col) = v;
        }
    }
}

// ---------------------------------------------------------------------------
// fused f+g projection: fg[row][0..31] = x@Wf+bf (bf16), [32..63] = x@Wg+bg
// tile 128 rows x 64 cols, microtile 4x8
// ---------------------------------------------------------------------------
__global__ __launch_bounds__(256) void gemm_fg(
    const float* __restrict__ A, const float* __restrict__ Wf,
    const float* __restrict__ bfv, const float* __restrict__ Wg,
    const float* __restrict__ bgv, u16* __restrict__ fg, int K)
{
    __shared__ float At[16][132];
    __shared__ float Wt[16][72];

    const int t  = threadIdx.x;
    const int tx = t & 7, ty = t >> 3;
    const int bm = blockIdx.x * 128;

    float acc[4][8];
#pragma unroll
    for (int i = 0; i < 4; ++i)
#pragma unroll
        for (int j = 0; j < 8; ++j) acc[i][j] = 0.f;

    for (int k0 = 0; k0 < K; k0 += 16) {
#pragma unroll
        for (int it = 0; it < 2; ++it) {
            int idx4 = t + 256 * it;
            int row  = idx4 >> 2;
            int c4   = (idx4 & 3) << 2;
            float4 v = *reinterpret_cast<const float4*>(
                A + (size_t)(bm + row) * K + k0 + c4);
            At[c4 + 0][row] = v.x; At[c4 + 1][row] = v.y;
            At[c4 + 2][row] = v.z; At[c4 + 3][row] = v.w;
        }
        {
            int k  = t >> 4;
            int n4 = (t & 15) << 2;
            float4 v;
            if (n4 < 32)
                v = *reinterpret_cast<const float4*>(Wf + (size_t)(k0 + k) * 32 + n4);
            else
                v = *reinterpret_cast<const float4*>(Wg + (size_t)(k0 + k) * 32 + n4 - 32);
            *reinterpret_cast<float4*>(&Wt[k][n4]) = v;
        }
        __syncthreads();

#pragma unroll
        for (int k = 0; k < 16; ++k) {
            float4 a4 = *reinterpret_cast<const float4*>(&At[k][ty * 4]);
            float4 w0 = *reinterpret_cast<const float4*>(&Wt[k][tx * 8]);
            float4 w1 = *reinterpret_cast<const float4*>(&Wt[k][tx * 8 + 4]);
            float a[4] = {a4.x, a4.y, a4.z, a4.w};
            float w[8] = {w0.x, w0.y, w0.z, w0.w, w1.x, w1.y, w1.z, w1.w};
#pragma unroll
            for (int i = 0; i < 4; ++i)
#pragma unroll
                for (int j = 0; j < 8; ++j)
                    acc[i][j] = fmaf(a[i], w[j], acc[i][j]);
        }
        __syncthreads();
    }

#pragma unroll
    for (int i = 0; i < 4; ++i) {
        int row = bm + ty * 4 + i;
        bf16x8 v;
#pragma unroll
        for (int j = 0; j < 8; ++j) {
            int col = tx * 8 + j;
            float bias = (col < 32) ? bfv[col] : bgv[col - 32];
            v[j] = (short)f2bf(acc[i][j] + bias);
        }
        *reinterpret_cast<bf16x8*>(fg + (size_t)row * 64 + tx * 8) = v;
    }
}

// ---------------------------------------------------------------------------
// h projection, TRANSPOSED bf16 output: hm_t[b][c][n] = (x@Wh+bh)^T
// same compute as gemm128; epilogue packs 8 rows (n-contig) per col -> 16B st
// ---------------------------------------------------------------------------
__global__ __launch_bounds__(256) void gemm_ht(
    const float* __restrict__ A, const float* __restrict__ W,
    const float* __restrict__ bias, u16* __restrict__ hmt, int K, int Nc)
{
    __shared__ float At[16][132];
    __shared__ float Wt[16][132];

    const int t  = threadIdx.x;
    const int tx = t & 15, ty = t >> 4;
    const int bm = blockIdx.x * 128;
    const int bn = blockIdx.y * 128;

    float acc[8][8];
#pragma unroll
    for (int i = 0; i < 8; ++i)
#pragma unroll
        for (int j = 0; j < 8; ++j) acc[i][j] = 0.f;

    for (int k0 = 0; k0 < K; k0 += 16) {
#pragma unroll
        for (int it = 0; it < 2; ++it) {
            int idx4 = t + 256 * it;
            int row  = idx4 >> 2;
            int c4   = (idx4 & 3) << 2;
            float4 v = *reinterpret_cast<const float4*>(
                A + (size_t)(bm + row) * K + k0 + c4);
            At[c4 + 0][row] = v.x; At[c4 + 1][row] = v.y;
            At[c4 + 2][row] = v.z; At[c4 + 3][row] = v.w;
        }
#pragma unroll
        for (int it = 0; it < 2; ++it) {
            int idx4 = t + 256 * it;
            int k    = idx4 >> 5;
            int n4   = (idx4 & 31) << 2;
            float4 v = *reinterpret_cast<const float4*>(
                W + (size_t)(k0 + k) * Nc + bn + n4);
            *reinterpret_cast<float4*>(&Wt[k][n4]) = v;
        }
        __syncthreads();

#pragma unroll
        for (int k = 0; k < 16; ++k) {
            float4 a0 = *reinterpret_cast<const float4*>(&At[k][ty * 8]);
            float4 a1 = *reinterpret_cast<const float4*>(&At[k][ty * 8 + 4]);
            float4 w0 = *reinterpret_cast<const float4*>(&Wt[k][tx * 8]);
            float4 w1 = *reinterpret_cast<const float4*>(&Wt[k][tx * 8 + 4]);
            float a[8] = {a0.x, a0.y, a0.z, a0.w, a1.x, a1.y, a1.z, a1.w};
            float w[8] = {w0.x, w0.y, w0.z, w0.w, w1.x, w1.y, w1.z, w1.w};
#pragma unroll
            for (int i = 0; i < 8; ++i)
#pragma unroll
                for (int j = 0; j < 8; ++j)
                    acc[i][j] = fmaf(a[i], w[j], acc[i][j]);
        }
        __syncthreads();
    }

    const int bb = bm >> 12;          // batch (128 | 4096)
    const int n0 = (bm & 4095) + ty * 8;
#pragma unroll
    for (int j = 0; j < 8; ++j) {
        int c = bn + tx * 8 + j;
        float bv = bias[c];
        bf16x8 v;
#pragma unroll
        for (int i = 0; i < 8; ++i) v[i] = (short)f2bf(acc[i][j] + bv);
        *reinterpret_cast<bf16x8*>(
            hmt + ((size_t)bb * 256 + c) * 4096 + n0) = v;
    }
}

// ---------------------------------------------------------------------------
// Flash attention, bf16 MFMA (16x16x32):
//  block: batch b, 64 query rows; iterate 64 key-tiles of 64 keys.
//  wave w: S strip rows w*16..+15 (4 MFMA) + softmax; PV cols w*64..+63
//  (32 MFMA, accumulating O frags f32).
// ---------------------------------------------------------------------------
__global__ __launch_bounds__(256) void attn_mfma(
    const u16* __restrict__ fg, const u16* __restrict__ hmt,
    float* __restrict__ obuf)
{
    __shared__ u16 vt[16384];       // V tile, chunk-swizzled [128 chunks][16 l16][8]
    __shared__ u16 fl[2048];        // F tile, [ct][quad][l16][8]
    __shared__ u16 pl[64 * 72];     // P tile [row][key], stride 72 (144B, 16B-aligned)
    __shared__ float alpha_l[64];
    __shared__ float lfin_l[64];

    const int t    = threadIdx.x;
    const int w    = t >> 6;
    const int lane = t & 63;
    const int quad = lane >> 4;
    const int l16  = lane & 15;
    const int b    = blockIdx.x >> 6;
    const int qt   = blockIdx.x & 63;

    const size_t fg_base = (size_t)b * 4096 * 64;
    const size_t hm_base = (size_t)b * 256 * 4096;

    // G A-frag: rows w*16+l16, ch quad*8..+7 (g = fg cols 32..63)
    const bf16x8 gfrag = *reinterpret_cast<const bf16x8*>(
        fg + fg_base + (size_t)(qt * 64 + w * 16 + l16) * 64 + 32 + quad * 8);

    f32x4 oacc[4][4];
#pragma unroll
    for (int mt = 0; mt < 4; ++mt)
#pragma unroll
        for (int nt = 0; nt < 4; ++nt)
#pragma unroll
            for (int r = 0; r < 4; ++r) oacc[mt][nt][r] = 0.f;

    float mrun[4], lrun[4];
#pragma unroll
    for (int r = 0; r < 4; ++r) { mrun[r] = -3.0e38f; lrun[r] = 0.f; }

    const f32x4 zero4 = {0.f, 0.f, 0.f, 0.f};

    for (int kt = 0; kt < 64; ++kt) {
        __syncthreads();   // prev PV reads of vt/pl done before restage

        // stage V tile (32 KB): 8 x 1KB wave-issues; swizzled so B-frag reads
        // are lane-consecutive 16B.
#pragma unroll
        for (int i = 0; i < 8; ++i) {
            int gi    = w * 8 + i;
            int chunk = gi * 4 + quad;                 // (c_hi<<3)|(kh<<2)|q
            int c     = ((chunk >> 3) << 4) + l16;
            int koff  = ((chunk >> 2) & 1) * 32 + (chunk & 3) * 8;
            const u16* gp = hmt + hm_base + (size_t)c * 4096 + kt * 64 + koff;
            ASYNC_CP16(gp, &vt[gi * 512]);
        }
        // stage F tile (4 KB): 1 issue/wave; wave w covers keys ct=w
        {
            const u16* gp = fg + fg_base +
                (size_t)(kt * 64 + w * 16 + l16) * 64 + quad * 8;
            ASYNC_CP16(gp, &fl[w * 512]);
        }
        __syncthreads();   // vmcnt drained at barrier -> tiles visible

        // ---- S = G @ F^T, strip rows w*16..+15 ----
        f32x4 sacc[4];
#pragma unroll
        for (int ct = 0; ct < 4; ++ct) {
            bf16x8 fb = *reinterpret_cast<const bf16x8*>(
                &fl[ct * 512 + quad * 128 + l16 * 8]);
            sacc[ct] = __builtin_amdgcn_mfma_f32_16x16x32_bf16(
                gfrag, fb, zero4, 0, 0, 0);
        }

        // ---- online softmax (row = w*16 + quad*4 + r, col = ct*16+l16) ----
        float al[4];
#pragma unroll
        for (int r = 0; r < 4; ++r) {
            float mx = fmaxf(fmaxf(sacc[0][r], sacc[1][r]),
                             fmaxf(sacc[2][r], sacc[3][r]));
            mx = fmaxf(mx, __shfl_xor(mx, 1));
            mx = fmaxf(mx, __shfl_xor(mx, 2));
            mx = fmaxf(mx, __shfl_xor(mx, 4));
            mx = fmaxf(mx, __shfl_xor(mx, 8));
            float mnew = fmaxf(mrun[r], mx);
            al[r] = __expf(mrun[r] - mnew);
            float ps = 0.f;
#pragma unroll
            for (int ct = 0; ct < 4; ++ct) {
                float p = __expf(sacc[ct][r] - mnew);
                ps += p;
                pl[(w * 16 + quad * 4 + r) * 72 + ct * 16 + l16] = f2bf(p);
            }
            ps += __shfl_xor(ps, 1);
            ps += __shfl_xor(ps, 2);
            ps += __shfl_xor(ps, 4);
            ps += __shfl_xor(ps, 8);
            lrun[r] = lrun[r] * al[r] + ps;
            mrun[r] = mnew;
        }
        if (l16 == 0) {
#pragma unroll
            for (int r = 0; r < 4; ++r)
                alpha_l[w * 16 + quad * 4 + r] = al[r];
        }
        __syncthreads();   // P, alpha visible

        // ---- O rescale + O += P @ V  (wave w: cols w*64..+63) ----
#pragma unroll
        for (int mt = 0; mt < 4; ++mt) {
            f32x4 av = *reinterpret_cast<const f32x4*>(&alpha_l[mt * 16 + quad * 4]);
#pragma unroll
            for (int nt = 0; nt < 4; ++nt)
#pragma unroll
                for (int r = 0; r < 4; ++r) oacc[mt][nt][r] *= av[r];
        }
        bf16x8 pa[4][2];
#pragma unroll
        for (int mt = 0; mt < 4; ++mt)
#pragma unroll
            for (int kh = 0; kh < 2; ++kh)
                pa[mt][kh] = *reinterpret_cast<const bf16x8*>(
                    &pl[(mt * 16 + l16) * 72 + kh * 32 + quad * 8]);
#pragma unroll
        for (int nt = 0; nt < 4; ++nt) {
#pragma unroll
            for (int kh = 0; kh < 2; ++kh) {
                bf16x8 vb = *reinterpret_cast<const bf16x8*>(
                    &vt[(((w * 4 + nt) * 8 + kh * 4 + quad) << 7) + l16 * 8]);
#pragma unroll
                for (int mt = 0; mt < 4; ++mt)
                    oacc[mt][nt] = __builtin_amdgcn_mfma_f32_16x16x32_bf16(
                        pa[mt][kh], vb, oacc[mt][nt], 0, 0, 0);
            }
        }
    }

    if (l16 == 0) {
#pragma unroll
        for (int r = 0; r < 4; ++r)
            lfin_l[w * 16 + quad * 4 + r] = lrun[r];
    }
    __syncthreads();

#pragma unroll
    for (int mt = 0; mt < 4; ++mt) {
        f32x4 lv = *reinterpret_cast<const f32x4*>(&lfin_l[mt * 16 + quad * 4]);
        float inv[4];
#pragma unroll
        for (int r = 0; r < 4; ++r) inv[r] = 1.f / lv[r];
#pragma unroll
        for (int nt = 0; nt < 4; ++nt) {
            float* op = obuf +
                ((size_t)b * 4096 + qt * 64 + mt * 16 + quad * 4) * 256 +
                w * 64 + nt * 16 + l16;
#pragma unroll
            for (int r = 0; r < 4; ++r)
                op[(size_t)r * 256] = oacc[mt][nt][r] * inv[r];
        }
    }
}

// ---------------------------------------------------------------------------
extern "C" void kernel_launch(void* const* d_in, const int* in_sizes, int n_in,
                              void* d_out, int out_size, void* d_ws, size_t ws_size,
                              hipStream_t stream)
{
    const float* x  = (const float*)d_in[0];
    const float* Wf = (const float*)d_in[1];
    const float* bf = (const float*)d_in[2];
    const float* Wg = (const float*)d_in[3];
    const float* bg = (const float*)d_in[4];
    const float* Wh = (const float*)d_in[5];
    const float* bh = (const float*)d_in[6];
    const float* Wv = (const float*)d_in[7];
    const float* bv = (const float*)d_in[8];
    float* out = (float*)d_out;

    const int M = 16384, C = 256;

    u16*   fgbuf = (u16*)d_ws;                       // 2 MB
    u16*   hmt   = fgbuf + (size_t)M * 64;           // 8 MB
    float* obuf  = (float*)(hmt + (size_t)4 * 256 * 4096);  // 16 MB

    dim3 blk(256);

    gemm_fg<<<dim3(M / 128), blk, 0, stream>>>(x, Wf, bf, Wg, bg, fgbuf, C);
    gemm_ht<<<dim3(M / 128, 2), blk, 0, stream>>>(x, Wh, bh, hmt, C, C);
    attn_mfma<<<dim3(256), blk, 0, stream>>>(fgbuf, hmt, obuf);
    gemm128<<<dim3(M / 128, 2), blk, 0, stream>>>(obuf, Wv, bv, x, out, M, C, C);
}

// Round 3
// 266.009 us; speedup vs baseline: 9.8276x; 1.3760x over previous
//
#include <hip/hip_runtime.h>
#include <math.h>

// B=4, H=W=64, C=256, Ck=32, N=4096, M=B*N=16384
// ws: fg bf16 [4][4096][64] (f=cols0..31, g=cols32..63) | hmt bf16 [4][256][4096]
//     | lpart f32 [S][16384] | opart f32 [S][16384][256]

typedef unsigned short u16;
typedef __attribute__((ext_vector_type(8))) short  bf16x8;
typedef __attribute__((ext_vector_type(4))) float  f32x4;

__device__ inline u16 f2bf(float x) {
    unsigned u = __float_as_uint(x);
    unsigned r = (u + 0x7fffu + ((u >> 16) & 1u)) >> 16;
    return (u16)r;
}

#define ASYNC_CP16(gp, lp)                                                     \
    __builtin_amdgcn_global_load_lds(                                          \
        (const __attribute__((address_space(1))) void*)(gp),                   \
        (__attribute__((address_space(3))) void*)(lp), 16, 0, 0)

// ---------------------------------------------------------------------------
// fused f+g projection: fg[row][0..31] = x@Wf+bf (bf16), [32..63] = x@Wg+bg
// ---------------------------------------------------------------------------
__global__ __launch_bounds__(256) void gemm_fg(
    const float* __restrict__ A, const float* __restrict__ Wf,
    const float* __restrict__ bfv, const float* __restrict__ Wg,
    const float* __restrict__ bgv, u16* __restrict__ fg, int K)
{
    __shared__ float At[16][132];
    __shared__ float Wt[16][72];

    const int t  = threadIdx.x;
    const int tx = t & 7, ty = t >> 3;
    const int bm = blockIdx.x * 128;

    float acc[4][8];
#pragma unroll
    for (int i = 0; i < 4; ++i)
#pragma unroll
        for (int j = 0; j < 8; ++j) acc[i][j] = 0.f;

    for (int k0 = 0; k0 < K; k0 += 16) {
#pragma unroll
        for (int it = 0; it < 2; ++it) {
            int idx4 = t + 256 * it;
            int row  = idx4 >> 2;
            int c4   = (idx4 & 3) << 2;
            float4 v = *reinterpret_cast<const float4*>(
                A + (size_t)(bm + row) * K + k0 + c4);
            At[c4 + 0][row] = v.x; At[c4 + 1][row] = v.y;
            At[c4 + 2][row] = v.z; At[c4 + 3][row] = v.w;
        }
        {
            int k  = t >> 4;
            int n4 = (t & 15) << 2;
            float4 v;
            if (n4 < 32)
                v = *reinterpret_cast<const float4*>(Wf + (size_t)(k0 + k) * 32 + n4);
            else
                v = *reinterpret_cast<const float4*>(Wg + (size_t)(k0 + k) * 32 + n4 - 32);
            *reinterpret_cast<float4*>(&Wt[k][n4]) = v;
        }
        __syncthreads();

#pragma unroll
        for (int k = 0; k < 16; ++k) {
            float4 a4 = *reinterpret_cast<const float4*>(&At[k][ty * 4]);
            float4 w0 = *reinterpret_cast<const float4*>(&Wt[k][tx * 8]);
            float4 w1 = *reinterpret_cast<const float4*>(&Wt[k][tx * 8 + 4]);
            float a[4] = {a4.x, a4.y, a4.z, a4.w};
            float w[8] = {w0.x, w0.y, w0.z, w0.w, w1.x, w1.y, w1.z, w1.w};
#pragma unroll
            for (int i = 0; i < 4; ++i)
#pragma unroll
                for (int j = 0; j < 8; ++j)
                    acc[i][j] = fmaf(a[i], w[j], acc[i][j]);
        }
        __syncthreads();
    }

#pragma unroll
    for (int i = 0; i < 4; ++i) {
        int row = bm + ty * 4 + i;
        bf16x8 v;
#pragma unroll
        for (int j = 0; j < 8; ++j) {
            int col = tx * 8 + j;
            float bias = (col < 32) ? bfv[col] : bgv[col - 32];
            v[j] = (short)f2bf(acc[i][j] + bias);
        }
        *reinterpret_cast<bf16x8*>(fg + (size_t)row * 64 + tx * 8) = v;
    }
}

// ---------------------------------------------------------------------------
// h projection, TRANSPOSED bf16 output: hmt[b][c][n] = (x@Wh+bh)^T
// ---------------------------------------------------------------------------
__global__ __launch_bounds__(256) void gemm_ht(
    const float* __restrict__ A, const float* __restrict__ W,
    const float* __restrict__ bias, u16* __restrict__ hmt, int K, int Nc)
{
    __shared__ float At[16][132];
    __shared__ float Wt[16][132];

    const int t  = threadIdx.x;
    const int tx = t & 15, ty = t >> 4;
    const int bm = blockIdx.x * 128;
    const int bn = blockIdx.y * 128;

    float acc[8][8];
#pragma unroll
    for (int i = 0; i < 8; ++i)
#pragma unroll
        for (int j = 0; j < 8; ++j) acc[i][j] = 0.f;

    for (int k0 = 0; k0 < K; k0 += 16) {
#pragma unroll
        for (int it = 0; it < 2; ++it) {
            int idx4 = t + 256 * it;
            int row  = idx4 >> 2;
            int c4   = (idx4 & 3) << 2;
            float4 v = *reinterpret_cast<const float4*>(
                A + (size_t)(bm + row) * K + k0 + c4);
            At[c4 + 0][row] = v.x; At[c4 + 1][row] = v.y;
            At[c4 + 2][row] = v.z; At[c4 + 3][row] = v.w;
        }
#pragma unroll
        for (int it = 0; it < 2; ++it) {
            int idx4 = t + 256 * it;
            int k    = idx4 >> 5;
            int n4   = (idx4 & 31) << 2;
            float4 v = *reinterpret_cast<const float4*>(
                W + (size_t)(k0 + k) * Nc + bn + n4);
            *reinterpret_cast<float4*>(&Wt[k][n4]) = v;
        }
        __syncthreads();

#pragma unroll
        for (int k = 0; k < 16; ++k) {
            float4 a0 = *reinterpret_cast<const float4*>(&At[k][ty * 8]);
            float4 a1 = *reinterpret_cast<const float4*>(&At[k][ty * 8 + 4]);
            float4 w0 = *reinterpret_cast<const float4*>(&Wt[k][tx * 8]);
            float4 w1 = *reinterpret_cast<const float4*>(&Wt[k][tx * 8 + 4]);
            float a[8] = {a0.x, a0.y, a0.z, a0.w, a1.x, a1.y, a1.z, a1.w};
            float w[8] = {w0.x, w0.y, w0.z, w0.w, w1.x, w1.y, w1.z, w1.w};
#pragma unroll
            for (int i = 0; i < 8; ++i)
#pragma unroll
                for (int j = 0; j < 8; ++j)
                    acc[i][j] = fmaf(a[i], w[j], acc[i][j]);
        }
        __syncthreads();
    }

    const int bb = bm >> 12;
    const int n0 = (bm & 4095) + ty * 8;
#pragma unroll
    for (int j = 0; j < 8; ++j) {
        int c = bn + tx * 8 + j;
        float bv = bias[c];
        bf16x8 v;
#pragma unroll
        for (int i = 0; i < 8; ++i) v[i] = (short)f2bf(acc[i][j] + bv);
        *reinterpret_cast<bf16x8*>(
            hmt + ((size_t)bb * 256 + c) * 4096 + n0) = v;
    }
}

// ---------------------------------------------------------------------------
// Flash attention v2 (no-max softmax, split-K, V direct from global):
//  block: (b, qt, ks). 64 queries, keys [ks*nkt*128, ...), 128-key tiles.
//  wave w: S rows w*16..+15 (8 MFMA); PV cols w*64..+63 (64 MFMA).
//  F double-buffered LDS (async); P in XOR-swizzled LDS (conflict-free);
//  V frags loaded straight from L2 (hmt is channel-major).
//  Emits RAW o (unnormalized) + l partials; final GEMM normalizes.
// ---------------------------------------------------------------------------
__global__ __launch_bounds__(256) void attn2(
    const u16* __restrict__ fg, const u16* __restrict__ hmt,
    float* __restrict__ opart, float* __restrict__ lpart, int ksl)
{
    __shared__ u16 fl[2][4096];   // F dbuf: [ct(8)][quad(4)][l16(16)][8]
    __shared__ u16 pl[64 * 128];  // P: row*128 + (col ^ (((row>>2)&3)*16))

    const int t    = threadIdx.x;
    const int w    = t >> 6;
    const int lane = t & 63;
    const int quad = lane >> 4;
    const int l16  = lane & 15;
    const int ks   = blockIdx.x & ((1 << ksl) - 1);
    const int qt   = (blockIdx.x >> ksl) & 63;
    const int b    = blockIdx.x >> (ksl + 6);
    const int nkt  = 32 >> ksl;
    const int kt0  = ks * nkt;

    const size_t fg_base = (size_t)b * 4096 * 64;
    const size_t hm_base = (size_t)b * 256 * 4096;

    // G A-frag: row qt*64 + w*16 + l16, ch quad*8..+7 (g = fg cols 32..63)
    const bf16x8 gfrag = *reinterpret_cast<const bf16x8*>(
        fg + fg_base + (size_t)(qt * 64 + w * 16 + l16) * 64 + 32 + quad * 8);

    f32x4 oacc[4][4];
#pragma unroll
    for (int mt = 0; mt < 4; ++mt)
#pragma unroll
        for (int nt = 0; nt < 4; ++nt)
#pragma unroll
            for (int r = 0; r < 4; ++r) oacc[mt][nt][r] = 0.f;

    float lsum[4] = {0.f, 0.f, 0.f, 0.f};
    const f32x4 zero4 = {0.f, 0.f, 0.f, 0.f};

    // prologue: stage F(kt0) into buf 0 (wave w covers ct = 2w, 2w+1)
    {
        const u16* gp = fg + fg_base +
            (size_t)(kt0 * 128 + (2 * w) * 16 + l16) * 64 + quad * 8;
        ASYNC_CP16(gp, &fl[0][(2 * w) * 512]);
        ASYNC_CP16(gp + 16 * 64, &fl[0][(2 * w + 1) * 512]);
    }

    for (int it = 0; it < nkt; ++it) {
        const int kt  = kt0 + it;
        const int buf = it & 1;
        __syncthreads();   // B1: pl reusable; (it==0) also publishes F(0)

        // hoist V frags for this tile (L2-resident; S-phase hides latency)
        bf16x8 vbr[4][4];
#pragma unroll
        for (int nt = 0; nt < 4; ++nt)
#pragma unroll
            for (int kh = 0; kh < 4; ++kh)
                vbr[nt][kh] = *reinterpret_cast<const bf16x8*>(
                    hmt + hm_base + (size_t)(w * 64 + nt * 16 + l16) * 4096 +
                    kt * 128 + kh * 32 + quad * 8);

        // ---- S = G @ F^T, rows w*16..+15, 128 keys ----
        f32x4 sacc[8];
#pragma unroll
        for (int ct = 0; ct < 8; ++ct) {
            bf16x8 fb = *reinterpret_cast<const bf16x8*>(
                &fl[buf][ct * 512 + quad * 128 + l16 * 8]);
            sacc[ct] = __builtin_amdgcn_mfma_f32_16x16x32_bf16(
                gfrag, fb, zero4, 0, 0, 0);
        }

        // ---- p = exp(s) (no max), write swizzled P, accumulate l ----
#pragma unroll
        for (int ct = 0; ct < 8; ++ct) {
#pragma unroll
            for (int r = 0; r < 4; ++r) {
                float p = __expf(sacc[ct][r]);
                lsum[r] += p;
                int row = w * 16 + quad * 4 + r;
                int col = ct * 16 + l16;
                pl[row * 128 + (col ^ (quad * 16))] = f2bf(p);
            }
        }

        // stage F(kt+1) into other buffer (its last reader synced at B2(it-1))
        if (it + 1 < nkt) {
            const u16* gp = fg + fg_base +
                (size_t)((kt + 1) * 128 + (2 * w) * 16 + l16) * 64 + quad * 8;
            ASYNC_CP16(gp, &fl[buf ^ 1][(2 * w) * 512]);
            ASYNC_CP16(gp + 16 * 64, &fl[buf ^ 1][(2 * w + 1) * 512]);
        }
        __syncthreads();   // B2: publish P; drains F(kt+1) + vbr loads

        // ---- O += P @ V  (wave w: cols w*64..+63) ----
#pragma unroll
        for (int kh = 0; kh < 4; ++kh) {
            bf16x8 pa[4];
#pragma unroll
            for (int mt = 0; mt < 4; ++mt)
                pa[mt] = *reinterpret_cast<const bf16x8*>(
                    &pl[(mt * 16 + l16) * 128 +
                        ((kh * 32 + quad * 8) ^ ((l16 & 12) << 2))]);
#pragma unroll
            for (int nt = 0; nt < 4; ++nt)
#pragma unroll
                for (int mt = 0; mt < 4; ++mt)
                    oacc[mt][nt] = __builtin_amdgcn_mfma_f32_16x16x32_bf16(
                        pa[mt], vbr[nt][kh], oacc[mt][nt], 0, 0, 0);
        }
    }

    // ---- epilogue: raw partials ----
#pragma unroll
    for (int r = 0; r < 4; ++r) {
        float s = lsum[r];
        s += __shfl_xor(s, 1);
        s += __shfl_xor(s, 2);
        s += __shfl_xor(s, 4);
        s += __shfl_xor(s, 8);
        lsum[r] = s;
    }
    if (l16 == 0) {
#pragma unroll
        for (int r = 0; r < 4; ++r)
            lpart[((size_t)ks << 14) + b * 4096 + qt * 64 + w * 16 + quad * 4 + r]
                = lsum[r];
    }
#pragma unroll
    for (int mt = 0; mt < 4; ++mt) {
#pragma unroll
        for (int nt = 0; nt < 4; ++nt) {
            float* op = opart + ((size_t)ks << 22) +
                ((size_t)(b * 4096 + qt * 64 + mt * 16 + quad * 4) * 256) +
                w * 64 + nt * 16 + l16;
#pragma unroll
            for (int r = 0; r < 4; ++r)
                op[(size_t)r * 256] = oacc[mt][nt][r];
        }
    }
}

// ---------------------------------------------------------------------------
// final conv with fused split-combine + normalize:
//   A[row][c] = (sum_s opart[s][row][c]) / (sum_s lpart[s][row])
//   out = A @ Wv + bv + x
// ---------------------------------------------------------------------------
__global__ __launch_bounds__(256) void gemm_final(
    const float* __restrict__ opart, const float* __restrict__ lpart, int S,
    const float* __restrict__ W, const float* __restrict__ bias,
    const float* __restrict__ res, float* __restrict__ out, int K, int Nc)
{
    __shared__ float At[16][132];
    __shared__ float Wt[16][132];

    const int t  = threadIdx.x;
    const int tx = t & 15, ty = t >> 4;
    const int bm = blockIdx.x * 128;
    const int bn = blockIdx.y * 128;

    // per-slot row normalizer (row fixed across K loop)
    float linv[2];
#pragma unroll
    for (int it = 0; it < 2; ++it) {
        int rg = bm + ((t + 256 * it) >> 2);
        float l = lpart[rg];
        if (S > 1) l += lpart[16384 + rg];
        linv[it] = 1.f / l;
    }

    float acc[8][8];
#pragma unroll
    for (int i = 0; i < 8; ++i)
#pragma unroll
        for (int j = 0; j < 8; ++j) acc[i][j] = 0.f;

    for (int k0 = 0; k0 < K; k0 += 16) {
#pragma unroll
        for (int it = 0; it < 2; ++it) {
            int idx4 = t + 256 * it;
            int row  = idx4 >> 2;
            int c4   = (idx4 & 3) << 2;
            size_t off = (size_t)(bm + row) * K + k0 + c4;
            float4 v = *reinterpret_cast<const float4*>(opart + off);
            if (S > 1) {
                float4 v2 = *reinterpret_cast<const float4*>(
                    opart + (1u << 22) + off);
                v.x += v2.x; v.y += v2.y; v.z += v2.z; v.w += v2.w;
            }
            float li = linv[it];
            At[c4 + 0][row] = v.x * li; At[c4 + 1][row] = v.y * li;
            At[c4 + 2][row] = v.z * li; At[c4 + 3][row] = v.w * li;
        }
#pragma unroll
        for (int it = 0; it < 2; ++it) {
            int idx4 = t + 256 * it;
            int k    = idx4 >> 5;
            int n4   = (idx4 & 31) << 2;
            float4 v = *reinterpret_cast<const float4*>(
                W + (size_t)(k0 + k) * Nc + bn + n4);
            *reinterpret_cast<float4*>(&Wt[k][n4]) = v;
        }
        __syncthreads();

#pragma unroll
        for (int k = 0; k < 16; ++k) {
            float4 a0 = *reinterpret_cast<const float4*>(&At[k][ty * 8]);
            float4 a1 = *reinterpret_cast<const float4*>(&At[k][ty * 8 + 4]);
            float4 w0 = *reinterpret_cast<const float4*>(&Wt[k][tx * 8]);
            float4 w1 = *reinterpret_cast<const float4*>(&Wt[k][tx * 8 + 4]);
            float a[8] = {a0.x, a0.y, a0.z, a0.w, a1.x, a1.y, a1.z, a1.w};
            float w[8] = {w0.x, w0.y, w0.z, w0.w, w1.x, w1.y, w1.z, w1.w};
#pragma unroll
            for (int i = 0; i < 8; ++i)
#pragma unroll
                for (int j = 0; j < 8; ++j)
                    acc[i][j] = fmaf(a[i], w[j], acc[i][j]);
        }
        __syncthreads();
    }

#pragma unroll
    for (int i = 0; i < 8; ++i) {
        int row = bm + ty * 8 + i;
#pragma unroll
        for (int j4 = 0; j4 < 2; ++j4) {
            int col = bn + tx * 8 + j4 * 4;
            float4 v;
            v.x = acc[i][j4 * 4 + 0] + bias[col + 0];
            v.y = acc[i][j4 * 4 + 1] + bias[col + 1];
            v.z = acc[i][j4 * 4 + 2] + bias[col + 2];
            v.w = acc[i][j4 * 4 + 3] + bias[col + 3];
            float4 r = *reinterpret_cast<const float4*>(
                res + (size_t)row * Nc + col);
            v.x += r.x; v.y += r.y; v.z += r.z; v.w += r.w;
            *reinterpret_cast<float4*>(out + (size_t)row * Nc + col) = v;
        }
    }
}

// ---------------------------------------------------------------------------
extern "C" void kernel_launch(void* const* d_in, const int* in_sizes, int n_in,
                              void* d_out, int out_size, void* d_ws, size_t ws_size,
                              hipStream_t stream)
{
    const float* x  = (const float*)d_in[0];
    const float* Wf = (const float*)d_in[1];
    const float* bf = (const float*)d_in[2];
    const float* Wg = (const float*)d_in[3];
    const float* bg = (const float*)d_in[4];
    const float* Wh = (const float*)d_in[5];
    const float* bh = (const float*)d_in[6];
    const float* Wv = (const float*)d_in[7];
    const float* bv = (const float*)d_in[8];
    float* out = (float*)d_out;

    const int M = 16384, C = 256;

    // ws: fg (2 MB) | hmt (8 MB) | lpart (S*64 KB) | opart (S*16 MB)
    const size_t fg_bytes = (size_t)M * 64 * 2;
    const size_t hm_bytes = (size_t)4 * 256 * 4096 * 2;
    const size_t need2 = fg_bytes + hm_bytes +
                         2 * ((size_t)M * 4 + (size_t)M * 256 * 4);
    const int ksl = (ws_size >= need2) ? 1 : 0;   // S = 2 if it fits
    const int S   = 1 << ksl;

    u16*   fgbuf = (u16*)d_ws;
    u16*   hmt   = fgbuf + (size_t)M * 64;
    float* lpart = (float*)(hmt + (size_t)4 * 256 * 4096);
    float* opart = lpart + (size_t)S * M;

    dim3 blk(256);

    gemm_fg<<<dim3(M / 128), blk, 0, stream>>>(x, Wf, bf, Wg, bg, fgbuf, C);
    gemm_ht<<<dim3(M / 128, 2), blk, 0, stream>>>(x, Wh, bh, hmt, C, C);
    attn2<<<dim3(256 * S), blk, 0, stream>>>(fgbuf, hmt, opart, lpart, ksl);
    gemm_final<<<dim3(M / 128, 2), blk, 0, stream>>>(
        opart, lpart, S, Wv, bv, x, out, C, C);
}

// Round 4
// 228.283 us; speedup vs baseline: 11.4517x; 1.1653x over previous
//
#include <hip/hip_runtime.h>
#include <math.h>

// B=4, H=W=64, C=256, Ck=32, N=4096, M=B*N=16384
// ws: fg bf16 [16384][64] (f=cols0..31, g=cols32..63)
//   | hmt bf16 [4][256][4096] (channel-major)
//   | wT bf16 [576][256]  (rows 0..31 Wf^T, 32..63 Wg^T, 64..319 Wh^T, 320..575 Wv^T)
//   | lpart f32 [S][16384] | opart f32 [S][16384][256]

typedef unsigned short u16;
typedef __attribute__((ext_vector_type(8))) short  bf16x8;
typedef __attribute__((ext_vector_type(4))) float  f32x4;

__device__ inline u16 f2bf(float x) {
    unsigned u = __float_as_uint(x);
    unsigned r = (u + 0x7fffu + ((u >> 16) & 1u)) >> 16;
    return (u16)r;
}

__device__ inline bf16x8 cvt8(float4 a, float4 b) {
    bf16x8 r;
    r[0] = (short)f2bf(a.x); r[1] = (short)f2bf(a.y);
    r[2] = (short)f2bf(a.z); r[3] = (short)f2bf(a.w);
    r[4] = (short)f2bf(b.x); r[5] = (short)f2bf(b.y);
    r[6] = (short)f2bf(b.z); r[7] = (short)f2bf(b.w);
    return r;
}

#define ASYNC_CP16(gp, lp)                                                     \
    __builtin_amdgcn_global_load_lds(                                          \
        (const __attribute__((address_space(1))) void*)(gp),                   \
        (__attribute__((address_space(3))) void*)(lp), 16, 0, 0)

// ---------------------------------------------------------------------------
// prep: pack weights transposed to bf16.  wT[n][k], n = concat col index.
// ---------------------------------------------------------------------------
__global__ __launch_bounds__(256) void prep_w(
    const float* __restrict__ Wf, const float* __restrict__ Wg,
    const float* __restrict__ Wh, const float* __restrict__ Wv,
    u16* __restrict__ wT)
{
    const int n = blockIdx.x;
    const int k = threadIdx.x;
    float v;
    if (n < 32)        v = Wf[(size_t)k * 32 + n];
    else if (n < 64)   v = Wg[(size_t)k * 32 + n - 32];
    else if (n < 320)  v = Wh[(size_t)k * 256 + n - 64];
    else               v = Wv[(size_t)k * 256 + n - 320];
    wT[(size_t)n * 256 + k] = f2bf(v);
}

// ---------------------------------------------------------------------------
// proj: Y[16384, 320] = x @ [Wf|Wg|Wh] + bias, bf16 MFMA, no LDS.
// block = 32 rows; wave w = cols w*80..+79 (5 n-tiles).
// cols 0..63 -> fg row-major; cols 64..319 -> hmt channel-major (8B stores).
// ---------------------------------------------------------------------------
__global__ __launch_bounds__(256) void proj_mfma(
    const float* __restrict__ x, const u16* __restrict__ wT,
    const float* __restrict__ bfv, const float* __restrict__ bgv,
    const float* __restrict__ bhv,
    u16* __restrict__ fg, u16* __restrict__ hmt)
{
    const int t    = threadIdx.x;
    const int w    = t >> 6;
    const int lane = t & 63;
    const int quad = lane >> 4;
    const int l16  = lane & 15;
    const int m0   = blockIdx.x * 32;
    const int wb   = w * 80;

    f32x4 acc[2][5];
#pragma unroll
    for (int mt = 0; mt < 2; ++mt)
#pragma unroll
        for (int nt = 0; nt < 5; ++nt)
#pragma unroll
            for (int r = 0; r < 4; ++r) acc[mt][nt][r] = 0.f;

#pragma unroll 2
    for (int ks = 0; ks < 8; ++ks) {
        bf16x8 afrag[2];
#pragma unroll
        for (int mt = 0; mt < 2; ++mt) {
            const float* xp = x + (size_t)(m0 + mt * 16 + l16) * 256 +
                              ks * 32 + quad * 8;
            float4 a0 = *reinterpret_cast<const float4*>(xp);
            float4 a1 = *reinterpret_cast<const float4*>(xp + 4);
            afrag[mt] = cvt8(a0, a1);
        }
#pragma unroll
        for (int nt = 0; nt < 5; ++nt) {
            bf16x8 bfrag = *reinterpret_cast<const bf16x8*>(
                wT + (size_t)(wb + nt * 16 + l16) * 256 + ks * 32 + quad * 8);
#pragma unroll
            for (int mt = 0; mt < 2; ++mt)
                acc[mt][nt] = __builtin_amdgcn_mfma_f32_16x16x32_bf16(
                    afrag[mt], bfrag, acc[mt][nt], 0, 0, 0);
        }
    }

    const int bb   = m0 >> 12;
    const int npix = m0 & 4095;
#pragma unroll
    for (int nt = 0; nt < 5; ++nt) {
        int col = wb + nt * 16 + l16;
        if (col < 64) {
            float bias = (col < 32) ? bfv[col] : bgv[col - 32];
#pragma unroll
            for (int mt = 0; mt < 2; ++mt) {
                int row = m0 + mt * 16 + quad * 4;
#pragma unroll
                for (int r = 0; r < 4; ++r)
                    fg[(size_t)(row + r) * 64 + col] =
                        f2bf(acc[mt][nt][r] + bias);
            }
        } else {
            int c = col - 64;
            float bias = bhv[c];
#pragma unroll
            for (int mt = 0; mt < 2; ++mt) {
                int n0 = npix + mt * 16 + quad * 4;
                ushort4 hv;
                hv.x = f2bf(acc[mt][nt][0] + bias);
                hv.y = f2bf(acc[mt][nt][1] + bias);
                hv.z = f2bf(acc[mt][nt][2] + bias);
                hv.w = f2bf(acc[mt][nt][3] + bias);
                *reinterpret_cast<ushort4*>(
                    hmt + ((size_t)bb * 256 + c) * 4096 + n0) = hv;
            }
        }
    }
}

// ---------------------------------------------------------------------------
// Flash attention (no-max softmax, split-K, V direct from L2):
//  block: (b, qt, ks). 64 queries, 128-key tiles, nkt = 32>>ksl tiles.
//  wave w: S rows w*16..+15 (8 MFMA); PV cols w*64..+63 (64 MFMA).
//  Emits RAW o + l partials; final GEMM normalizes.
// ---------------------------------------------------------------------------
__global__ __launch_bounds__(256) void attn2(
    const u16* __restrict__ fg, const u16* __restrict__ hmt,
    float* __restrict__ opart, float* __restrict__ lpart, int ksl)
{
    __shared__ u16 fl[2][4096];   // F dbuf: [ct(8)][quad(4)][l16(16)][8]
    __shared__ u16 pl[64 * 128];  // P: row*128 + (col ^ (quad*16))

    const int t    = threadIdx.x;
    const int w    = t >> 6;
    const int lane = t & 63;
    const int quad = lane >> 4;
    const int l16  = lane & 15;
    const int ks   = blockIdx.x & ((1 << ksl) - 1);
    const int qt   = (blockIdx.x >> ksl) & 63;
    const int b    = blockIdx.x >> (ksl + 6);
    const int nkt  = 32 >> ksl;
    const int kt0  = ks * nkt;

    const size_t fg_base = (size_t)b * 4096 * 64;
    const size_t hm_base = (size_t)b * 256 * 4096;

    const bf16x8 gfrag = *reinterpret_cast<const bf16x8*>(
        fg + fg_base + (size_t)(qt * 64 + w * 16 + l16) * 64 + 32 + quad * 8);

    f32x4 oacc[4][4];
#pragma unroll
    for (int mt = 0; mt < 4; ++mt)
#pragma unroll
        for (int nt = 0; nt < 4; ++nt)
#pragma unroll
            for (int r = 0; r < 4; ++r) oacc[mt][nt][r] = 0.f;

    float lsum[4] = {0.f, 0.f, 0.f, 0.f};
    const f32x4 zero4 = {0.f, 0.f, 0.f, 0.f};

    {
        const u16* gp = fg + fg_base +
            (size_t)(kt0 * 128 + (2 * w) * 16 + l16) * 64 + quad * 8;
        ASYNC_CP16(gp, &fl[0][(2 * w) * 512]);
        ASYNC_CP16(gp + 16 * 64, &fl[0][(2 * w + 1) * 512]);
    }

    for (int it = 0; it < nkt; ++it) {
        const int kt  = kt0 + it;
        const int buf = it & 1;
        __syncthreads();   // B1: pl reusable; (it==0) also publishes F(0)

        bf16x8 vbr[4][4];
#pragma unroll
        for (int nt = 0; nt < 4; ++nt)
#pragma unroll
            for (int kh = 0; kh < 4; ++kh)
                vbr[nt][kh] = *reinterpret_cast<const bf16x8*>(
                    hmt + hm_base + (size_t)(w * 64 + nt * 16 + l16) * 4096 +
                    kt * 128 + kh * 32 + quad * 8);

        f32x4 sacc[8];
#pragma unroll
        for (int ct = 0; ct < 8; ++ct) {
            bf16x8 fb = *reinterpret_cast<const bf16x8*>(
                &fl[buf][ct * 512 + quad * 128 + l16 * 8]);
            sacc[ct] = __builtin_amdgcn_mfma_f32_16x16x32_bf16(
                gfrag, fb, zero4, 0, 0, 0);
        }

#pragma unroll
        for (int ct = 0; ct < 8; ++ct) {
#pragma unroll
            for (int r = 0; r < 4; ++r) {
                float p = __expf(sacc[ct][r]);
                lsum[r] += p;
                int row = w * 16 + quad * 4 + r;
                int col = ct * 16 + l16;
                pl[row * 128 + (col ^ (quad * 16))] = f2bf(p);
            }
        }

        if (it + 1 < nkt) {
            const u16* gp = fg + fg_base +
                (size_t)((kt + 1) * 128 + (2 * w) * 16 + l16) * 64 + quad * 8;
            ASYNC_CP16(gp, &fl[buf ^ 1][(2 * w) * 512]);
            ASYNC_CP16(gp + 16 * 64, &fl[buf ^ 1][(2 * w + 1) * 512]);
        }
        __syncthreads();   // B2: publish P; drains F(kt+1) + vbr loads

#pragma unroll
        for (int kh = 0; kh < 4; ++kh) {
            bf16x8 pa[4];
#pragma unroll
            for (int mt = 0; mt < 4; ++mt)
                pa[mt] = *reinterpret_cast<const bf16x8*>(
                    &pl[(mt * 16 + l16) * 128 +
                        ((kh * 32 + quad * 8) ^ ((l16 & 12) << 2))]);
#pragma unroll
            for (int nt = 0; nt < 4; ++nt)
#pragma unroll
                for (int mt = 0; mt < 4; ++mt)
                    oacc[mt][nt] = __builtin_amdgcn_mfma_f32_16x16x32_bf16(
                        pa[mt], vbr[nt][kh], oacc[mt][nt], 0, 0, 0);
        }
    }

#pragma unroll
    for (int r = 0; r < 4; ++r) {
        float s = lsum[r];
        s += __shfl_xor(s, 1);
        s += __shfl_xor(s, 2);
        s += __shfl_xor(s, 4);
        s += __shfl_xor(s, 8);
        lsum[r] = s;
    }
    if (l16 == 0) {
#pragma unroll
        for (int r = 0; r < 4; ++r)
            lpart[((size_t)ks << 14) + b * 4096 + qt * 64 + w * 16 + quad * 4 + r]
                = lsum[r];
    }
#pragma unroll
    for (int mt = 0; mt < 4; ++mt) {
#pragma unroll
        for (int nt = 0; nt < 4; ++nt) {
            float* op = opart + ((size_t)ks << 22) +
                ((size_t)(b * 4096 + qt * 64 + mt * 16 + quad * 4) * 256) +
                w * 64 + nt * 16 + l16;
#pragma unroll
            for (int r = 0; r < 4; ++r)
                op[(size_t)r * 256] = oacc[mt][nt][r];
        }
    }
}

// ---------------------------------------------------------------------------
// final: out = x + ((sum_s opart[s]) / lsum) @ Wv + bv, bf16 MFMA, no LDS.
// block = 32 rows; wave w = cols w*64..+63 (4 n-tiles).
// ---------------------------------------------------------------------------
__global__ __launch_bounds__(256) void final_mfma(
    const float* __restrict__ opart, const float* __restrict__ lpart, int S,
    const u16* __restrict__ wT, const float* __restrict__ bvv,
    const float* __restrict__ x, float* __restrict__ out)
{
    const int t    = threadIdx.x;
    const int w    = t >> 6;
    const int lane = t & 63;
    const int quad = lane >> 4;
    const int l16  = lane & 15;
    const int m0   = blockIdx.x * 32;
    const int wb   = w * 64;

    float linv[2];
#pragma unroll
    for (int mt = 0; mt < 2; ++mt) {
        int row = m0 + mt * 16 + l16;
        float l = lpart[row];
        for (int s = 1; s < S; ++s) l += lpart[(size_t)s * 16384 + row];
        linv[mt] = 1.f / l;
    }

    f32x4 acc[2][4];
#pragma unroll
    for (int mt = 0; mt < 2; ++mt)
#pragma unroll
        for (int nt = 0; nt < 4; ++nt)
#pragma unroll
            for (int r = 0; r < 4; ++r) acc[mt][nt][r] = 0.f;

#pragma unroll 2
    for (int ks = 0; ks < 8; ++ks) {
        bf16x8 afrag[2];
#pragma unroll
        for (int mt = 0; mt < 2; ++mt) {
            size_t off = (size_t)(m0 + mt * 16 + l16) * 256 + ks * 32 + quad * 8;
            float4 a0 = *reinterpret_cast<const float4*>(opart + off);
            float4 a1 = *reinterpret_cast<const float4*>(opart + off + 4);
            for (int s = 1; s < S; ++s) {
                size_t so = ((size_t)s << 22) + off;
                float4 b0 = *reinterpret_cast<const float4*>(opart + so);
                float4 b1 = *reinterpret_cast<const float4*>(opart + so + 4);
                a0.x += b0.x; a0.y += b0.y; a0.z += b0.z; a0.w += b0.w;
                a1.x += b1.x; a1.y += b1.y; a1.z += b1.z; a1.w += b1.w;
            }
            float li = linv[mt];
            a0.x *= li; a0.y *= li; a0.z *= li; a0.w *= li;
            a1.x *= li; a1.y *= li; a1.z *= li; a1.w *= li;
            afrag[mt] = cvt8(a0, a1);
        }
#pragma unroll
        for (int nt = 0; nt < 4; ++nt) {
            bf16x8 bfrag = *reinterpret_cast<const bf16x8*>(
                wT + (size_t)(320 + wb + nt * 16 + l16) * 256 +
                ks * 32 + quad * 8);
#pragma unroll
            for (int mt = 0; mt < 2; ++mt)
                acc[mt][nt] = __builtin_amdgcn_mfma_f32_16x16x32_bf16(
                    afrag[mt], bfrag, acc[mt][nt], 0, 0, 0);
        }
    }

#pragma unroll
    for (int nt = 0; nt < 4; ++nt) {
        int col = wb + nt * 16 + l16;
        float bias = bvv[col];
#pragma unroll
        for (int mt = 0; mt < 2; ++mt) {
            int row = m0 + mt * 16 + quad * 4;
#pragma unroll
            for (int r = 0; r < 4; ++r) {
                size_t off = (size_t)(row + r) * 256 + col;
                out[off] = acc[mt][nt][r] + bias + x[off];
            }
        }
    }
}

// ---------------------------------------------------------------------------
extern "C" void kernel_launch(void* const* d_in, const int* in_sizes, int n_in,
                              void* d_out, int out_size, void* d_ws, size_t ws_size,
                              hipStream_t stream)
{
    const float* x  = (const float*)d_in[0];
    const float* Wf = (const float*)d_in[1];
    const float* bf = (const float*)d_in[2];
    const float* Wg = (const float*)d_in[3];
    const float* bg = (const float*)d_in[4];
    const float* Wh = (const float*)d_in[5];
    const float* bh = (const float*)d_in[6];
    const float* Wv = (const float*)d_in[7];
    const float* bv = (const float*)d_in[8];
    float* out = (float*)d_out;

    const int M = 16384;

    const size_t base_b = (size_t)M * 64 * 2 + (size_t)4 * 256 * 4096 * 2 +
                          (size_t)576 * 256 * 2;
    const size_t per_s  = (size_t)M * 4 + (size_t)M * 256 * 4;
    int ksl = 0;
    if (ws_size >= base_b + 4 * per_s)      ksl = 2;
    else if (ws_size >= base_b + 2 * per_s) ksl = 1;
    const int S = 1 << ksl;

    u16*   fgbuf = (u16*)d_ws;
    u16*   hmt   = fgbuf + (size_t)M * 64;
    u16*   wT    = hmt + (size_t)4 * 256 * 4096;
    float* lpart = (float*)(wT + (size_t)576 * 256);
    float* opart = lpart + (size_t)S * M;

    dim3 blk(256);

    prep_w<<<dim3(576), blk, 0, stream>>>(Wf, Wg, Wh, Wv, wT);
    proj_mfma<<<dim3(M / 32), blk, 0, stream>>>(x, wT, bf, bg, bh, fgbuf, hmt);
    attn2<<<dim3(256 * S), blk, 0, stream>>>(fgbuf, hmt, opart, lpart, ksl);
    final_mfma<<<dim3(M / 32), blk, 0, stream>>>(
        opart, lpart, S, wT, bv, x, out);
}